// Round 19
// baseline (120.691 us; speedup 1.0000x reference)
//
#include <hip/hip_runtime.h>
#include <hip/hip_bf16.h>

typedef __attribute__((ext_vector_type(8))) short bf16x8;
typedef __attribute__((ext_vector_type(4))) short short4v;
typedef __attribute__((ext_vector_type(4))) float f32x4;
typedef __attribute__((ext_vector_type(16))) float f32x16;
typedef __attribute__((ext_vector_type(4))) float float4v;

__device__ __forceinline__ short f2bf(float f) {
    union { float f; unsigned u; } v; v.f = f;
    unsigned r = v.u + 0x7fffu + ((v.u >> 16) & 1u);
    return (short)(r >> 16);
}
__device__ __forceinline__ float bf2f(short s) {
    union { unsigned u; float f; } v;
    v.u = ((unsigned)(unsigned short)s) << 16;
    return v.f;
}

__device__ __forceinline__ void gload16(const short* g, short* lds) {
    __builtin_amdgcn_global_load_lds(
        (const __attribute__((address_space(1))) unsigned*)g,
        (__attribute__((address_space(3))) unsigned*)lds, 16, 0, 0);
}

// ---------------- transpose+convert tile body: in [K][N] fp32 -> out [N][K] bf16
__device__ __forceinline__ void tconv_tile(const float* __restrict__ in,
                                           short* __restrict__ out,
                                           int Kdim, int Ndim, int n0, int k0) {
    __shared__ int Ls[64][65];
    const int t = threadIdx.x;
    const int kl = t >> 4, n4 = (t & 15) * 4;
#pragma unroll
    for (int it = 0; it < 4; ++it) {
        int k = kl + it * 16;
        float4v v = *reinterpret_cast<const float4v*>(&in[(size_t)(k0 + k) * Ndim + n0 + n4]);
#pragma unroll
        for (int c = 0; c < 4; ++c) Ls[k][n4 + c] = (int)(unsigned short)f2bf(v[c]);
    }
    __syncthreads();
    const int nl0 = t >> 4, kq = (t & 15) * 4;
#pragma unroll
    for (int it = 0; it < 4; ++it) {
        int nl = nl0 + it * 16;
        short4v s;
#pragma unroll
        for (int j = 0; j < 4; ++j) s[j] = (short)Ls[kq + j][nl];
        *reinterpret_cast<short4v*>(&out[(size_t)(n0 + nl) * Kdim + k0 + kq]) = s;
    }
}

// ---------------- prep1: blocks [0,2048) = hidden fp32->bf16 ; [2048,2816) = w_attn transpose
__global__ __launch_bounds__(256) void prep1(const float* __restrict__ hidden,
                                             short* __restrict__ Ah,
                                             const float* __restrict__ w_attn,
                                             short* __restrict__ Wta) {
    const int bx = blockIdx.x;
    if (bx < 2048) {
        int i = (bx * 256 + threadIdx.x) * 8;
        float4v a0 = *reinterpret_cast<const float4v*>(&hidden[i]);
        float4v a1 = *reinterpret_cast<const float4v*>(&hidden[i + 4]);
        bf16x8 s;
        s[0] = f2bf(a0[0]); s[1] = f2bf(a0[1]); s[2] = f2bf(a0[2]); s[3] = f2bf(a0[3]);
        s[4] = f2bf(a1[0]); s[5] = f2bf(a1[1]); s[6] = f2bf(a1[2]); s[7] = f2bf(a1[3]);
        *reinterpret_cast<bf16x8*>(&Ah[i]) = s;
    } else {
        int idx = bx - 2048;                       // 0..767 = 48 x 16
        int n0 = (idx % 48) * 64, k0 = (idx / 48) * 64;
        tconv_tile(w_attn, Wta, 1024, 3072, n0, k0);
    }
}

// ---------------- GEMM1: QKV = Ah[4096,1024](bf16) x Wt[3072,1024](bf16 [n][k])
// 64x64 tiles -> 3072 blocks (12/CU-worth) for latency hiding; XCD-chunked 16mt x 24nt.
__global__ __launch_bounds__(256) void qkv_gemm(const short* __restrict__ Ah,
                                                const short* __restrict__ Wt,
                                                short* __restrict__ Qw,
                                                short* __restrict__ Kw,
                                                short* __restrict__ Vt) {
    __shared__ short As[64 * 64];
    __shared__ short Bs[64 * 64];
    const int tid = threadIdx.x;
    const int l = tid & 63, w = tid >> 6;
    const int g = l >> 4, lr = l & 15;
    const int r8 = l >> 3, sl = l & 7;
    const int xs = (sl ^ r8) * 8;
    const int wm = (w >> 1) * 32, wn = (w & 1) * 32;
    const int bid = blockIdx.x;
    const int xcd = bid & 7, idx = bid >> 3;          // idx 0..383
    const int mt = (xcd >> 1) * 16 + idx / 24;        // 0..63
    const int nt = (xcd & 1) * 24 + idx % 24;         // 0..47
    const int m0 = mt * 64;
    const int n0 = nt * 64;
    const bool isV = (n0 >= 2048);
    f32x4 acc[2][2] = {};
    for (int k0 = 0; k0 < 1024; k0 += 64) {
        const short* Ag = Ah + m0 * 1024 + k0;
        const short* Bg = Wt + n0 * 1024 + k0;
#pragma unroll
        for (int i = 0; i < 2; ++i) {
            int seg = w * 2 + i;
            gload16(Ag + (seg * 8 + r8) * 1024 + xs, &As[seg * 512]);
            gload16(Bg + (seg * 8 + r8) * 1024 + xs, &Bs[seg * 512]);
        }
        __syncthreads();
#pragma unroll
        for (int kk = 0; kk < 2; ++kk) {
            bf16x8 af[2], bfr[2];
#pragma unroll
            for (int mi = 0; mi < 2; ++mi) {
                int row = wm + mi * 16 + lr;
                af[mi] = *reinterpret_cast<const bf16x8*>(&As[row * 64 + (((4 * kk + g) ^ (lr & 7)) * 8)]);
            }
#pragma unroll
            for (int ni = 0; ni < 2; ++ni) {
                int col = wn + ni * 16 + lr;
                bfr[ni] = *reinterpret_cast<const bf16x8*>(&Bs[col * 64 + (((4 * kk + g) ^ (lr & 7)) * 8)]);
            }
            if (isV) {
#pragma unroll
                for (int mi = 0; mi < 2; ++mi)
#pragma unroll
                    for (int ni = 0; ni < 2; ++ni)
                        acc[mi][ni] = __builtin_amdgcn_mfma_f32_16x16x32_bf16(af[mi], bfr[ni], acc[mi][ni], 0, 0, 0);
            } else {
                // swapped: per-lane regs = 4 consecutive d -> vector stores
#pragma unroll
                for (int mi = 0; mi < 2; ++mi)
#pragma unroll
                    for (int ni = 0; ni < 2; ++ni)
                        acc[mi][ni] = __builtin_amdgcn_mfma_f32_16x16x32_bf16(bfr[ni], af[mi], acc[mi][ni], 0, 0, 0);
            }
        }
        __syncthreads();
    }
    if (isV) {
#pragma unroll
        for (int mi = 0; mi < 2; ++mi) {
            int m = m0 + wm + mi * 16 + g * 4;
            int bb = m >> 11, s0 = m & 2047;
#pragma unroll
            for (int ni = 0; ni < 2; ++ni) {
                int n = n0 + wn + ni * 16 + lr;
                int hh = (n >> 6) & 15, d = n & 63;
                short4v pv;
#pragma unroll
                for (int r = 0; r < 4; ++r) pv[r] = f2bf(acc[mi][ni][r]);
                *reinterpret_cast<short4v*>(&Vt[(((bb * 16 + hh) * 64) + d) * 2048 + s0]) = pv;
            }
        }
    } else {
        const bool isQ = (n0 < 1024);
        const float sc = isQ ? 0.18033688011112042f : 1.0f;  // Q: 0.125*log2(e)
        short* dst = isQ ? Qw : Kw;
#pragma unroll
        for (int mi = 0; mi < 2; ++mi) {
            int m = m0 + wm + mi * 16 + lr;
            int bb = m >> 11, s0 = m & 2047;
#pragma unroll
            for (int ni = 0; ni < 2; ++ni) {
                int n = n0 + wn + ni * 16 + g * 4;
                int hh = (n >> 6) & 15, d = n & 63;
                float a0 = acc[mi][ni][0] * sc, a1 = acc[mi][ni][1] * sc;
                float a2 = acc[mi][ni][2] * sc, a3 = acc[mi][ni][3] * sc;
                int w0, w1;
                asm("v_cvt_pk_bf16_f32 %0, %1, %2" : "=v"(w0) : "v"(a0), "v"(a1));
                asm("v_cvt_pk_bf16_f32 %0, %1, %2" : "=v"(w1) : "v"(a2), "v"(a3));
                union { int wd[2]; short4v s; } u;
                u.wd[0] = w0; u.wd[1] = w1;
                *reinterpret_cast<short4v*>(&dst[((bb * 16 + hh) * 2048 + s0) * 64 + d]) = u.s;
            }
        }
    }
}

// ---------------- Attention v9: attn6s chassis + psum-via-MFMA(ones) + unnormalized partials.
__global__ __launch_bounds__(256, 4) void attn9(const short* __restrict__ Qw,
                                                const short* __restrict__ Kw,
                                                const short* __restrict__ Vt,
                                                short* __restrict__ N0,
                                                short* __restrict__ N1,
                                                float* __restrict__ Tot) {
    __shared__ short Ks[2][64 * 64];
    __shared__ short Vs[2][64 * 64];
    const int tid = threadIdx.x;
    const int w = tid >> 6, l = tid & 63;
    const int q = l & 31, hi = l >> 5;
    const int r8 = l >> 3, sl = l & 7;
    const int xs = (sl ^ r8) * 8;
    const int bid = blockIdx.x;
    const int work = (bid & 7) * 128 + (bid >> 3);
    const int head = work >> 5;
    const int qblk = (work & 31) >> 1;
    const int ks = work & 1;
    const int b = head >> 4, h = head & 15;
    const int q0 = qblk * 128 + w * 32;
    const short* Qb = Qw + ((b * 16 + h) * 2048 + q0) * 64;
    const short* Kb = Kw + ((b * 16 + h) * 2048 + ks * 1024) * 64;
    const short* Vb = Vt + ((b * 16 + h) * 64) * 2048 + ks * 1024;

    bf16x8 qb[4];
#pragma unroll
    for (int c = 0; c < 4; ++c)
        qb[c] = *reinterpret_cast<const bf16x8*>(&Qb[q * 64 + c * 16 + hi * 8]);

    bf16x8 ones1;
#pragma unroll
    for (int j = 0; j < 8; ++j) ones1[j] = (short)0x3F80;

    int koff[2][4], voff[2][2][2];
#pragma unroll
    for (int sub = 0; sub < 2; ++sub)
#pragma unroll
        for (int c = 0; c < 4; ++c)
            koff[sub][c] = (sub * 32 + q) * 64 + (((2 * c + hi) ^ (q & 7)) * 8);
#pragma unroll
    for (int sub = 0; sub < 2; ++sub)
#pragma unroll
        for (int c2 = 0; c2 < 2; ++c2)
#pragma unroll
            for (int dt = 0; dt < 2; ++dt)
                voff[sub][c2][dt] = (dt * 32 + q) * 64 + (((4 * sub + 2 * c2 + hi) ^ (q & 7)) * 8);

    f32x16 o0 = {}, o1 = {};
    f32x16 psacc = {};

#define STAGE_KV(buf, j0)                                                        \
    {                                                                            \
        _Pragma("unroll")                                                        \
        for (int i = 0; i < 2; ++i) {                                            \
            int seg = w * 2 + i;                                                 \
            gload16(Kb + ((j0) + seg * 8 + r8) * 64 + xs, &Ks[buf][seg * 512]);  \
            gload16(Vb + (seg * 8 + r8) * 2048 + (j0) + xs, &Vs[buf][seg * 512]);\
        }                                                                        \
    }

    STAGE_KV(0, 0);
    __syncthreads();
    int cur = 0;

    for (int jt = 0; jt < 16; ++jt) {
        if (jt < 15) STAGE_KV(cur ^ 1, (jt + 1) * 64);

#pragma unroll
        for (int sub = 0; sub < 2; ++sub) {
            f32x16 st = {};
            __builtin_amdgcn_s_setprio(1);
#pragma unroll
            for (int c = 0; c < 4; ++c) {
                bf16x8 ka = *reinterpret_cast<const bf16x8*>(&Ks[cur][koff[sub][c]]);
                st = __builtin_amdgcn_mfma_f32_32x32x16_bf16(ka, qb[c], st, 0, 0, 0);
            }
            __builtin_amdgcn_s_setprio(0);
            float p[16];
#pragma unroll
            for (int r = 0; r < 16; ++r) p[r] = __builtin_amdgcn_exp2f(st[r]);
            int pk[4][2];
#pragma unroll
            for (int bq = 0; bq < 4; ++bq) {
                int w0, w1;
                asm("v_cvt_pk_bf16_f32 %0, %1, %2" : "=v"(w0) : "v"(p[4 * bq]), "v"(p[4 * bq + 1]));
                asm("v_cvt_pk_bf16_f32 %0, %1, %2" : "=v"(w1) : "v"(p[4 * bq + 2]), "v"(p[4 * bq + 3]));
                pk[bq][0] = w0; pk[bq][1] = w1;
            }
#pragma unroll
            for (int c2 = 0; c2 < 2; ++c2) {
                int w0 = pk[2 * c2][0], w2 = pk[2 * c2 + 1][0];
                int w1 = pk[2 * c2][1], w3 = pk[2 * c2 + 1][1];
                asm("v_permlane32_swap_b32 %0, %1" : "+v"(w0), "+v"(w2));
                asm("v_permlane32_swap_b32 %0, %1" : "+v"(w1), "+v"(w3));
                union { int wd[4]; bf16x8 v; } pb;
                pb.wd[0] = w0; pb.wd[1] = w1; pb.wd[2] = w2; pb.wd[3] = w3;
                __builtin_amdgcn_s_setprio(1);
                psacc = __builtin_amdgcn_mfma_f32_32x32x16_bf16(ones1, pb.v, psacc, 0, 0, 0);
#pragma unroll
                for (int dt = 0; dt < 2; ++dt) {
                    bf16x8 va = *reinterpret_cast<const bf16x8*>(&Vs[cur][voff[sub][c2][dt]]);
                    if (dt == 0) o0 = __builtin_amdgcn_mfma_f32_32x32x16_bf16(va, pb.v, o0, 0, 0, 0);
                    else         o1 = __builtin_amdgcn_mfma_f32_32x32x16_bf16(va, pb.v, o1, 0, 0, 0);
                }
                __builtin_amdgcn_s_setprio(0);
            }
        }
        __syncthreads();
        cur ^= 1;
    }
#undef STAGE_KV

    float tot = psacc[0];

    short* Nd = ks ? N1 : N0;
    short* Orow = &Nd[(b * 2048 + q0 + q) * 1024 + h * 64];
#pragma unroll
    for (int r = 0; r < 4; ++r) {
        short4v ov0, ov1;
#pragma unroll
        for (int j = 0; j < 4; ++j) {
            ov0[j] = f2bf(o0[4 * r + j]);
            ov1[j] = f2bf(o1[4 * r + j]);
        }
        *reinterpret_cast<short4v*>(&Orow[8 * r + 4 * hi]) = ov0;
        *reinterpret_cast<short4v*>(&Orow[32 + 8 * r + 4 * hi]) = ov1;
    }
    if (hi == 0)
        Tot[ks * 65536 + (b * 16 + h) * 2048 + q0 + q] = tot;
}

// ---------------- post: blocks [0,2048) = merge halves ; [2048,2304) = w_proj transpose
__global__ __launch_bounds__(256) void post(short* __restrict__ N0,
                                            const short* __restrict__ N1,
                                            const float* __restrict__ Tot,
                                            const float* __restrict__ w_proj,
                                            short* __restrict__ Wtp) {
    const int bx = blockIdx.x;
    if (bx < 2048) {
        int i = (bx * 256 + threadIdx.x) * 8;
        int bs = i >> 10;
        int b = bs >> 11, s = bs & 2047;
        int h = (i >> 6) & 15;
        int qi = (b * 16 + h) * 2048 + s;
        float t0 = Tot[qi], t1 = Tot[65536 + qi];
        float inv = 1.f / (t0 + t1);
        bf16x8 a = *reinterpret_cast<const bf16x8*>(&N0[i]);
        bf16x8 c = *reinterpret_cast<const bf16x8*>(&N1[i]);
        bf16x8 r;
#pragma unroll
        for (int j = 0; j < 8; ++j) r[j] = f2bf((bf2f(a[j]) + bf2f(c[j])) * inv);
        *reinterpret_cast<bf16x8*>(&N0[i]) = r;
    } else {
        int idx = bx - 2048;                      // 0..255 = 16 x 16
        int n0 = (idx % 16) * 64, k0 = (idx / 16) * 64;
        tconv_tile(w_proj, Wtp, 1024, 1024, n0, k0);
    }
}

// ---------------- GEMM2: out = O[4096,1024](bf16) x Wtp[1024,1024](bf16 [n][k]) -> fp32
// 64x64 tiles -> 1024 blocks (4/CU) for latency hiding; XCD-chunked.
__global__ __launch_bounds__(256) void proj_gemm(const short* __restrict__ Ag,
                                                 const short* __restrict__ Wtp,
                                                 float* __restrict__ Out) {
    __shared__ short As[64 * 64];
    __shared__ short Bs[64 * 64];
    const int tid = threadIdx.x;
    const int l = tid & 63, w = tid >> 6;
    const int g = l >> 4, lr = l & 15;
    const int r8 = l >> 3, sl = l & 7;
    const int xs = (sl ^ r8) * 8;
    const int wm = (w >> 1) * 32, wn = (w & 1) * 32;
    const int bid = blockIdx.x;
    const int work = (bid & 7) * 128 + (bid >> 3);   // XCD-chunked: 8 x 128 works
    const int mt = work >> 4, nt = work & 15;        // mt 0..63, nt 0..15
    const int m0 = mt * 64;
    const int n0 = nt * 64;
    f32x4 acc[2][2] = {};
    for (int k0 = 0; k0 < 1024; k0 += 64) {
        const short* Ab = Ag + m0 * 1024 + k0;
        const short* Bg = Wtp + n0 * 1024 + k0;
#pragma unroll
        for (int i = 0; i < 2; ++i) {
            int seg = w * 2 + i;
            gload16(Ab + (seg * 8 + r8) * 1024 + xs, &As[seg * 512]);
            gload16(Bg + (seg * 8 + r8) * 1024 + xs, &Bs[seg * 512]);
        }
        __syncthreads();
#pragma unroll
        for (int kk = 0; kk < 2; ++kk) {
            bf16x8 af[2], bfr[2];
#pragma unroll
            for (int mi = 0; mi < 2; ++mi) {
                int row = wm + mi * 16 + lr;
                af[mi] = *reinterpret_cast<const bf16x8*>(&As[row * 64 + (((4 * kk + g) ^ (lr & 7)) * 8)]);
            }
#pragma unroll
            for (int ni = 0; ni < 2; ++ni) {
                int col = wn + ni * 16 + lr;
                bfr[ni] = *reinterpret_cast<const bf16x8*>(&Bs[col * 64 + (((4 * kk + g) ^ (lr & 7)) * 8)]);
            }
#pragma unroll
            for (int mi = 0; mi < 2; ++mi)
#pragma unroll
                for (int ni = 0; ni < 2; ++ni)
                    acc[mi][ni] = __builtin_amdgcn_mfma_f32_16x16x32_bf16(af[mi], bfr[ni], acc[mi][ni], 0, 0, 0);
        }
        __syncthreads();
    }
#pragma unroll
    for (int mi = 0; mi < 2; ++mi) {
#pragma unroll
        for (int ni = 0; ni < 2; ++ni) {
            int n = n0 + wn + ni * 16 + lr;
#pragma unroll
            for (int r = 0; r < 4; ++r) {
                int mm = m0 + wm + mi * 16 + g * 4 + r;
                Out[mm * 1024 + n] = acc[mi][ni][r];
            }
        }
    }
}

extern "C" void kernel_launch(void* const* d_in, const int* in_sizes, int n_in,
                              void* d_out, int out_size, void* d_ws, size_t ws_size,
                              hipStream_t stream) {
    const float* hidden = (const float*)d_in[0];
    const float* w_attn = (const float*)d_in[1];
    const float* w_proj = (const float*)d_in[2];
    float* out = (float*)d_out;

    // ws (32 MiB): [Ah -> later N0/O][Qw -> later Wtp][Kw][Vt]
    short* AhN0 = (short*)d_ws;
    short* Qw = AhN0 + 4194304;
    short* Kw = Qw + 4194304;
    short* Vt = Kw + 4194304;
    // d_out (16 MiB) scratch until proj overwrites: [0,6M) Wta | [7M,7.5M) Tot | [8M,16M) N1
    short* Wta = (short*)d_out;
    float* Tot = (float*)((char*)d_out + 7u * 1024 * 1024);
    short* N1 = (short*)((char*)d_out + 8u * 1024 * 1024);

    prep1<<<dim3(2816), 256, 0, stream>>>(hidden, AhN0, w_attn, Wta);
    qkv_gemm<<<dim3(3072), 256, 0, stream>>>(AhN0, Wta, Qw, Kw, Vt);
    attn9<<<dim3(1024), 256, 0, stream>>>(Qw, Kw, Vt, AhN0, N1, Tot);    // AhN0 = half-0 partial
    post<<<dim3(2304), 256, 0, stream>>>(AhN0, N1, Tot, w_proj, Qw);     // AhN0 = O, Qw = Wtp
    proj_gemm<<<dim3(1024), 256, 0, stream>>>(AhN0, Qw, out);
}

// Round 20
// 119.691 us; speedup vs baseline: 1.0084x; 1.0084x over previous
//
#include <hip/hip_runtime.h>
#include <hip/hip_bf16.h>

typedef __attribute__((ext_vector_type(8))) short bf16x8;
typedef __attribute__((ext_vector_type(4))) short short4v;
typedef __attribute__((ext_vector_type(4))) float f32x4;
typedef __attribute__((ext_vector_type(16))) float f32x16;
typedef __attribute__((ext_vector_type(4))) float float4v;

__device__ __forceinline__ short f2bf(float f) {
    union { float f; unsigned u; } v; v.f = f;
    unsigned r = v.u + 0x7fffu + ((v.u >> 16) & 1u);
    return (short)(r >> 16);
}
__device__ __forceinline__ float bf2f(short s) {
    union { unsigned u; float f; } v;
    v.u = ((unsigned)(unsigned short)s) << 16;
    return v.f;
}

__device__ __forceinline__ void gload16(const short* g, short* lds) {
    __builtin_amdgcn_global_load_lds(
        (const __attribute__((address_space(1))) unsigned*)g,
        (__attribute__((address_space(3))) unsigned*)lds, 16, 0, 0);
}

// ---------------- transpose+convert tile body: in [K][N] fp32 -> out [N][K] bf16
__device__ __forceinline__ void tconv_tile(const float* __restrict__ in,
                                           short* __restrict__ out,
                                           int Kdim, int Ndim, int n0, int k0) {
    __shared__ int Ls[64][65];
    const int t = threadIdx.x;
    const int kl = t >> 4, n4 = (t & 15) * 4;
#pragma unroll
    for (int it = 0; it < 4; ++it) {
        int k = kl + it * 16;
        float4v v = *reinterpret_cast<const float4v*>(&in[(size_t)(k0 + k) * Ndim + n0 + n4]);
#pragma unroll
        for (int c = 0; c < 4; ++c) Ls[k][n4 + c] = (int)(unsigned short)f2bf(v[c]);
    }
    __syncthreads();
    const int nl0 = t >> 4, kq = (t & 15) * 4;
#pragma unroll
    for (int it = 0; it < 4; ++it) {
        int nl = nl0 + it * 16;
        short4v s;
#pragma unroll
        for (int j = 0; j < 4; ++j) s[j] = (short)Ls[kq + j][nl];
        *reinterpret_cast<short4v*>(&out[(size_t)(n0 + nl) * Kdim + k0 + kq]) = s;
    }
}

// ---------------- prep1: blocks [0,2048) = hidden fp32->bf16 ; [2048,2816) = w_attn transpose
__global__ __launch_bounds__(256) void prep1(const float* __restrict__ hidden,
                                             short* __restrict__ Ah,
                                             const float* __restrict__ w_attn,
                                             short* __restrict__ Wta) {
    const int bx = blockIdx.x;
    if (bx < 2048) {
        int i = (bx * 256 + threadIdx.x) * 8;
        float4v a0 = *reinterpret_cast<const float4v*>(&hidden[i]);
        float4v a1 = *reinterpret_cast<const float4v*>(&hidden[i + 4]);
        bf16x8 s;
        s[0] = f2bf(a0[0]); s[1] = f2bf(a0[1]); s[2] = f2bf(a0[2]); s[3] = f2bf(a0[3]);
        s[4] = f2bf(a1[0]); s[5] = f2bf(a1[1]); s[6] = f2bf(a1[2]); s[7] = f2bf(a1[3]);
        *reinterpret_cast<bf16x8*>(&Ah[i]) = s;
    } else {
        int idx = bx - 2048;                       // 0..767 = 48 x 16
        int n0 = (idx % 48) * 64, k0 = (idx / 48) * 64;
        tconv_tile(w_attn, Wta, 1024, 3072, n0, k0);
    }
}

// ---------------- GEMM1: QKV = Ah[4096,1024](bf16) x Wt[3072,1024](bf16, [n][k])
__global__ __launch_bounds__(256) void qkv_gemm(const short* __restrict__ Ah,
                                                const short* __restrict__ Wt,
                                                short* __restrict__ Qw,
                                                short* __restrict__ Kw,
                                                short* __restrict__ Vt) {
    __shared__ short As[128 * 64];
    __shared__ short Bs[128 * 64];
    const int tid = threadIdx.x;
    const int l = tid & 63, w = tid >> 6;
    const int g = l >> 4, lr = l & 15;
    const int r8 = l >> 3, sl = l & 7;
    const int xs = (sl ^ r8) * 8;
    const int wm = (w >> 1) * 64, wn = (w & 1) * 64;
    const int bid = blockIdx.x;
    const int xcd = bid & 7, idx = bid >> 3;
    const int nt = (xcd & 1) * 12 + idx % 12;
    const int mt = (xcd >> 1) * 8 + idx / 12;
    const int m0 = mt * 128;
    const int n0 = nt * 128;
    const bool isV = (n0 >= 2048);
    f32x4 acc[4][4] = {};
    for (int k0 = 0; k0 < 1024; k0 += 64) {
        const short* Ag = Ah + m0 * 1024 + k0;
        const short* Bg = Wt + n0 * 1024 + k0;
#pragma unroll
        for (int i = 0; i < 4; ++i) {
            int seg = w * 4 + i;
            gload16(Ag + (seg * 8 + r8) * 1024 + xs, &As[seg * 512]);
            gload16(Bg + (seg * 8 + r8) * 1024 + xs, &Bs[seg * 512]);
        }
        __syncthreads();
#pragma unroll
        for (int kk = 0; kk < 2; ++kk) {
            bf16x8 af[4], bfr[4];
#pragma unroll
            for (int mi = 0; mi < 4; ++mi) {
                int row = wm + mi * 16 + lr;
                af[mi] = *reinterpret_cast<const bf16x8*>(&As[row * 64 + (((4 * kk + g) ^ (lr & 7)) * 8)]);
            }
#pragma unroll
            for (int ni = 0; ni < 4; ++ni) {
                int col = wn + ni * 16 + lr;
                bfr[ni] = *reinterpret_cast<const bf16x8*>(&Bs[col * 64 + (((4 * kk + g) ^ (lr & 7)) * 8)]);
            }
            if (isV) {
#pragma unroll
                for (int mi = 0; mi < 4; ++mi)
#pragma unroll
                    for (int ni = 0; ni < 4; ++ni)
                        acc[mi][ni] = __builtin_amdgcn_mfma_f32_16x16x32_bf16(af[mi], bfr[ni], acc[mi][ni], 0, 0, 0);
            } else {
#pragma unroll
                for (int mi = 0; mi < 4; ++mi)
#pragma unroll
                    for (int ni = 0; ni < 4; ++ni)
                        acc[mi][ni] = __builtin_amdgcn_mfma_f32_16x16x32_bf16(bfr[ni], af[mi], acc[mi][ni], 0, 0, 0);
            }
        }
        __syncthreads();
    }
    if (isV) {
#pragma unroll
        for (int mi = 0; mi < 4; ++mi) {
            int m = m0 + wm + mi * 16 + g * 4;
            int bb = m >> 11, s0 = m & 2047;
#pragma unroll
            for (int ni = 0; ni < 4; ++ni) {
                int n = n0 + wn + ni * 16 + lr;
                int hh = (n >> 6) & 15, d = n & 63;
                short4v pv;
#pragma unroll
                for (int r = 0; r < 4; ++r) pv[r] = f2bf(acc[mi][ni][r]);
                *reinterpret_cast<short4v*>(&Vt[(((bb * 16 + hh) * 64) + d) * 2048 + s0]) = pv;
            }
        }
    } else {
        const bool isQ = (n0 < 1024);
        const float sc = isQ ? 0.18033688011112042f : 1.0f;  // Q: 0.125*log2(e)
        short* dst = isQ ? Qw : Kw;
#pragma unroll
        for (int mi = 0; mi < 4; ++mi) {
            int m = m0 + wm + mi * 16 + lr;
            int bb = m >> 11, s0 = m & 2047;
#pragma unroll
            for (int ni = 0; ni < 4; ++ni) {
                int n = n0 + wn + ni * 16 + g * 4;
                int hh = (n >> 6) & 15, d = n & 63;
                float a0 = acc[mi][ni][0] * sc, a1 = acc[mi][ni][1] * sc;
                float a2 = acc[mi][ni][2] * sc, a3 = acc[mi][ni][3] * sc;
                int w0, w1;
                asm("v_cvt_pk_bf16_f32 %0, %1, %2" : "=v"(w0) : "v"(a0), "v"(a1));
                asm("v_cvt_pk_bf16_f32 %0, %1, %2" : "=v"(w1) : "v"(a2), "v"(a3));
                union { int wd[2]; short4v s; } u;
                u.wd[0] = w0; u.wd[1] = w1;
                *reinterpret_cast<short4v*>(&dst[((bb * 16 + hh) * 2048 + s0) * 64 + d]) = u.s;
            }
        }
    }
}

// ---------------- Attention v9: attn6s chassis + psum-via-MFMA(ones) + unnormalized partials.
__global__ __launch_bounds__(256, 4) void attn9(const short* __restrict__ Qw,
                                                const short* __restrict__ Kw,
                                                const short* __restrict__ Vt,
                                                short* __restrict__ N0,
                                                short* __restrict__ N1,
                                                float* __restrict__ Tot) {
    __shared__ short Ks[2][64 * 64];
    __shared__ short Vs[2][64 * 64];
    const int tid = threadIdx.x;
    const int w = tid >> 6, l = tid & 63;
    const int q = l & 31, hi = l >> 5;
    const int r8 = l >> 3, sl = l & 7;
    const int xs = (sl ^ r8) * 8;
    const int bid = blockIdx.x;
    const int work = (bid & 7) * 128 + (bid >> 3);
    const int head = work >> 5;
    const int qblk = (work & 31) >> 1;
    const int ks = work & 1;
    const int b = head >> 4, h = head & 15;
    const int q0 = qblk * 128 + w * 32;
    const short* Qb = Qw + ((b * 16 + h) * 2048 + q0) * 64;
    const short* Kb = Kw + ((b * 16 + h) * 2048 + ks * 1024) * 64;
    const short* Vb = Vt + ((b * 16 + h) * 64) * 2048 + ks * 1024;

    bf16x8 qb[4];
#pragma unroll
    for (int c = 0; c < 4; ++c)
        qb[c] = *reinterpret_cast<const bf16x8*>(&Qb[q * 64 + c * 16 + hi * 8]);

    bf16x8 ones1;
#pragma unroll
    for (int j = 0; j < 8; ++j) ones1[j] = (short)0x3F80;

    int koff[2][4], voff[2][2][2];
#pragma unroll
    for (int sub = 0; sub < 2; ++sub)
#pragma unroll
        for (int c = 0; c < 4; ++c)
            koff[sub][c] = (sub * 32 + q) * 64 + (((2 * c + hi) ^ (q & 7)) * 8);
#pragma unroll
    for (int sub = 0; sub < 2; ++sub)
#pragma unroll
        for (int c2 = 0; c2 < 2; ++c2)
#pragma unroll
            for (int dt = 0; dt < 2; ++dt)
                voff[sub][c2][dt] = (dt * 32 + q) * 64 + (((4 * sub + 2 * c2 + hi) ^ (q & 7)) * 8);

    f32x16 o0 = {}, o1 = {};
    f32x16 psacc = {};

#define STAGE_KV(buf, j0)                                                        \
    {                                                                            \
        _Pragma("unroll")                                                        \
        for (int i = 0; i < 2; ++i) {                                            \
            int seg = w * 2 + i;                                                 \
            gload16(Kb + ((j0) + seg * 8 + r8) * 64 + xs, &Ks[buf][seg * 512]);  \
            gload16(Vb + (seg * 8 + r8) * 2048 + (j0) + xs, &Vs[buf][seg * 512]);\
        }                                                                        \
    }

    STAGE_KV(0, 0);
    __syncthreads();
    int cur = 0;

    for (int jt = 0; jt < 16; ++jt) {
        if (jt < 15) STAGE_KV(cur ^ 1, (jt + 1) * 64);

#pragma unroll
        for (int sub = 0; sub < 2; ++sub) {
            f32x16 st = {};
            __builtin_amdgcn_s_setprio(1);
#pragma unroll
            for (int c = 0; c < 4; ++c) {
                bf16x8 ka = *reinterpret_cast<const bf16x8*>(&Ks[cur][koff[sub][c]]);
                st = __builtin_amdgcn_mfma_f32_32x32x16_bf16(ka, qb[c], st, 0, 0, 0);
            }
            __builtin_amdgcn_s_setprio(0);
            float p[16];
#pragma unroll
            for (int r = 0; r < 16; ++r) p[r] = __builtin_amdgcn_exp2f(st[r]);
            int pk[4][2];
#pragma unroll
            for (int bq = 0; bq < 4; ++bq) {
                int w0, w1;
                asm("v_cvt_pk_bf16_f32 %0, %1, %2" : "=v"(w0) : "v"(p[4 * bq]), "v"(p[4 * bq + 1]));
                asm("v_cvt_pk_bf16_f32 %0, %1, %2" : "=v"(w1) : "v"(p[4 * bq + 2]), "v"(p[4 * bq + 3]));
                pk[bq][0] = w0; pk[bq][1] = w1;
            }
#pragma unroll
            for (int c2 = 0; c2 < 2; ++c2) {
                int w0 = pk[2 * c2][0], w2 = pk[2 * c2 + 1][0];
                int w1 = pk[2 * c2][1], w3 = pk[2 * c2 + 1][1];
                asm("v_permlane32_swap_b32 %0, %1" : "+v"(w0), "+v"(w2));
                asm("v_permlane32_swap_b32 %0, %1" : "+v"(w1), "+v"(w3));
                union { int wd[4]; bf16x8 v; } pb;
                pb.wd[0] = w0; pb.wd[1] = w1; pb.wd[2] = w2; pb.wd[3] = w3;
                __builtin_amdgcn_s_setprio(1);
                psacc = __builtin_amdgcn_mfma_f32_32x32x16_bf16(ones1, pb.v, psacc, 0, 0, 0);
#pragma unroll
                for (int dt = 0; dt < 2; ++dt) {
                    bf16x8 va = *reinterpret_cast<const bf16x8*>(&Vs[cur][voff[sub][c2][dt]]);
                    if (dt == 0) o0 = __builtin_amdgcn_mfma_f32_32x32x16_bf16(va, pb.v, o0, 0, 0, 0);
                    else         o1 = __builtin_amdgcn_mfma_f32_32x32x16_bf16(va, pb.v, o1, 0, 0, 0);
                }
                __builtin_amdgcn_s_setprio(0);
            }
        }
        __syncthreads();
        cur ^= 1;
    }
#undef STAGE_KV

    float tot = psacc[0];

    short* Nd = ks ? N1 : N0;
    short* Orow = &Nd[(b * 2048 + q0 + q) * 1024 + h * 64];
#pragma unroll
    for (int r = 0; r < 4; ++r) {
        short4v ov0, ov1;
#pragma unroll
        for (int j = 0; j < 4; ++j) {
            ov0[j] = f2bf(o0[4 * r + j]);
            ov1[j] = f2bf(o1[4 * r + j]);
        }
        *reinterpret_cast<short4v*>(&Orow[8 * r + 4 * hi]) = ov0;
        *reinterpret_cast<short4v*>(&Orow[32 + 8 * r + 4 * hi]) = ov1;
    }
    if (hi == 0)
        Tot[ks * 65536 + (b * 16 + h) * 2048 + q0 + q] = tot;
}

// ---------------- post: blocks [0,2048) = merge halves ; [2048,2304) = w_proj transpose
__global__ __launch_bounds__(256) void post(short* __restrict__ N0,
                                            const short* __restrict__ N1,
                                            const float* __restrict__ Tot,
                                            const float* __restrict__ w_proj,
                                            short* __restrict__ Wtp) {
    const int bx = blockIdx.x;
    if (bx < 2048) {
        int i = (bx * 256 + threadIdx.x) * 8;
        int bs = i >> 10;
        int b = bs >> 11, s = bs & 2047;
        int h = (i >> 6) & 15;
        int qi = (b * 16 + h) * 2048 + s;
        float t0 = Tot[qi], t1 = Tot[65536 + qi];
        float inv = 1.f / (t0 + t1);
        bf16x8 a = *reinterpret_cast<const bf16x8*>(&N0[i]);
        bf16x8 c = *reinterpret_cast<const bf16x8*>(&N1[i]);
        bf16x8 r;
#pragma unroll
        for (int j = 0; j < 8; ++j) r[j] = f2bf((bf2f(a[j]) + bf2f(c[j])) * inv);
        *reinterpret_cast<bf16x8*>(&N0[i]) = r;
    } else {
        int idx = bx - 2048;                      // 0..255 = 16 x 16
        int n0 = (idx % 16) * 64, k0 = (idx / 16) * 64;
        tconv_tile(w_proj, Wtp, 1024, 1024, n0, k0);
    }
}

// ---------------- GEMM2: out = O[4096,1024](bf16) x Wtp[1024,1024](bf16 [n][k]) -> fp32
// 64x64 tiles -> 1024 blocks (4/CU) for latency hiding; XCD-chunked.
__global__ __launch_bounds__(256) void proj_gemm(const short* __restrict__ Ag,
                                                 const short* __restrict__ Wtp,
                                                 float* __restrict__ Out) {
    __shared__ short As[64 * 64];
    __shared__ short Bs[64 * 64];
    const int tid = threadIdx.x;
    const int l = tid & 63, w = tid >> 6;
    const int g = l >> 4, lr = l & 15;
    const int r8 = l >> 3, sl = l & 7;
    const int xs = (sl ^ r8) * 8;
    const int wm = (w >> 1) * 32, wn = (w & 1) * 32;
    const int bid = blockIdx.x;
    const int work = (bid & 7) * 128 + (bid >> 3);   // XCD-chunked: 8 x 128 works
    const int mt = work >> 4, nt = work & 15;        // mt 0..63, nt 0..15
    const int m0 = mt * 64;
    const int n0 = nt * 64;
    f32x4 acc[2][2] = {};
    for (int k0 = 0; k0 < 1024; k0 += 64) {
        const short* Ab = Ag + m0 * 1024 + k0;
        const short* Bg = Wtp + n0 * 1024 + k0;
#pragma unroll
        for (int i = 0; i < 2; ++i) {
            int seg = w * 2 + i;
            gload16(Ab + (seg * 8 + r8) * 1024 + xs, &As[seg * 512]);
            gload16(Bg + (seg * 8 + r8) * 1024 + xs, &Bs[seg * 512]);
        }
        __syncthreads();
#pragma unroll
        for (int kk = 0; kk < 2; ++kk) {
            bf16x8 af[2], bfr[2];
#pragma unroll
            for (int mi = 0; mi < 2; ++mi) {
                int row = wm + mi * 16 + lr;
                af[mi] = *reinterpret_cast<const bf16x8*>(&As[row * 64 + (((4 * kk + g) ^ (lr & 7)) * 8)]);
            }
#pragma unroll
            for (int ni = 0; ni < 2; ++ni) {
                int col = wn + ni * 16 + lr;
                bfr[ni] = *reinterpret_cast<const bf16x8*>(&Bs[col * 64 + (((4 * kk + g) ^ (lr & 7)) * 8)]);
            }
#pragma unroll
            for (int mi = 0; mi < 2; ++mi)
#pragma unroll
                for (int ni = 0; ni < 2; ++ni)
                    acc[mi][ni] = __builtin_amdgcn_mfma_f32_16x16x32_bf16(af[mi], bfr[ni], acc[mi][ni], 0, 0, 0);
        }
        __syncthreads();
    }
#pragma unroll
    for (int mi = 0; mi < 2; ++mi) {
#pragma unroll
        for (int ni = 0; ni < 2; ++ni) {
            int n = n0 + wn + ni * 16 + lr;
#pragma unroll
            for (int r = 0; r < 4; ++r) {
                int mm = m0 + wm + mi * 16 + g * 4 + r;
                Out[mm * 1024 + n] = acc[mi][ni][r];
            }
        }
    }
}

extern "C" void kernel_launch(void* const* d_in, const int* in_sizes, int n_in,
                              void* d_out, int out_size, void* d_ws, size_t ws_size,
                              hipStream_t stream) {
    const float* hidden = (const float*)d_in[0];
    const float* w_attn = (const float*)d_in[1];
    const float* w_proj = (const float*)d_in[2];
    float* out = (float*)d_out;

    // ws (32 MiB): [Ah -> later N0/O][Qw -> later Wtp][Kw][Vt]
    short* AhN0 = (short*)d_ws;
    short* Qw = AhN0 + 4194304;
    short* Kw = Qw + 4194304;
    short* Vt = Kw + 4194304;
    // d_out (16 MiB) scratch until proj overwrites: [0,6M) Wta | [7M,7.5M) Tot | [8M,16M) N1
    short* Wta = (short*)d_out;
    float* Tot = (float*)((char*)d_out + 7u * 1024 * 1024);
    short* N1 = (short*)((char*)d_out + 8u * 1024 * 1024);

    prep1<<<dim3(2816), 256, 0, stream>>>(hidden, AhN0, w_attn, Wta);
    qkv_gemm<<<dim3(768), 256, 0, stream>>>(AhN0, Wta, Qw, Kw, Vt);
    attn9<<<dim3(1024), 256, 0, stream>>>(Qw, Kw, Vt, AhN0, N1, Tot);    // AhN0 = half-0 partial
    post<<<dim3(2304), 256, 0, stream>>>(AhN0, N1, Tot, w_proj, Qw);     // AhN0 = O, Qw = Wtp
    proj_gemm<<<dim3(1024), 256, 0, stream>>>(AhN0, Qw, out);
}